// Round 1
// baseline (117.037 us; speedup 1.0000x reference)
//
#include <hip/hip_runtime.h>

// ConvertParamsLayerFrom0: B=2048, NH=128, NV=256
//   inv = rsqrt(covh_diag2)                     [B,NH]
//   wt2[b,h,v] = wt1[b,h,v] * inv[b,h]          [B,NH,NV]
//   b2[b,v]    = b1[b,v] - sum_h wt1[b,h,v] * (inv[b,h]*muh2[b,h])   [B,NV]
//
// Memory-bound: ~518 MiB traffic, floor ~86us @ 6.3 TB/s.

#define NB 2048
#define NH 128
#define NV 256

__global__ __launch_bounds__(256, 4) void convert_params_kernel(
    const float* __restrict__ b1,    // [B, NV]
    const float* __restrict__ wt1,   // [B, NH, NV]
    const float* __restrict__ muh2,  // [B, NH]
    const float* __restrict__ cov,   // [B, NH]
    float* __restrict__ b2,          // [B, NV]
    float* __restrict__ wt2)         // [B, NH, NV]
{
    const int b = blockIdx.x;
    const int t = threadIdx.x;

    __shared__ float s_inv[NH];      // rsqrt(cov)
    __shared__ float s_sm[NH];       // rsqrt(cov) * muh2
    __shared__ float s_red[4][NV];   // cross-h-group partial sums (4 KiB)

    // Stage per-(b,h) scalars in LDS.
    if (t < NH) {
        float c   = cov[(size_t)b * NH + t];
        float inv = rsqrtf(c);
        s_inv[t] = inv;
        s_sm[t]  = inv * muh2[(size_t)b * NH + t];
    }
    __syncthreads();

    // Layout: 4 h-groups x 64 lanes; each lane owns a float4 of v.
    const int lane = t & 63;         // 0..63  -> v4 = lane*4
    const int hg   = t >> 6;         // 0..3   -> h = hg, hg+4, hg+8, ...
    const int v4   = lane * 4;

    const float* wt1_b = wt1 + (size_t)b * NH * NV;
    float*       wt2_b = wt2 + (size_t)b * NH * NV;

    float ax = 0.f, ay = 0.f, az = 0.f, aw = 0.f;

    #pragma unroll 8
    for (int h = hg; h < NH; h += 4) {
        const float4 w = *reinterpret_cast<const float4*>(wt1_b + h * NV + v4);
        const float inv = s_inv[h];   // wave-uniform broadcast (free)
        const float sm  = s_sm[h];
        float4 o;
        o.x = w.x * inv; o.y = w.y * inv; o.z = w.z * inv; o.w = w.w * inv;
        *reinterpret_cast<float4*>(wt2_b + h * NV + v4) = o;
        ax = fmaf(w.x, sm, ax);
        ay = fmaf(w.y, sm, ay);
        az = fmaf(w.z, sm, az);
        aw = fmaf(w.w, sm, aw);
    }

    // Reduce the 4 h-group partials via LDS, then write b2 (wave 0 only).
    s_red[hg][v4 + 0] = ax;
    s_red[hg][v4 + 1] = ay;
    s_red[hg][v4 + 2] = az;
    s_red[hg][v4 + 3] = aw;
    __syncthreads();

    if (hg == 0) {
        // lane covers v4..v4+3
        #pragma unroll
        for (int j = 0; j < 4; ++j) {
            const int v = v4 + j;
            const float sum = s_red[0][v] + s_red[1][v] + s_red[2][v] + s_red[3][v];
            b2[(size_t)b * NV + v] = b1[(size_t)b * NV + v] - sum;
        }
    }
}

extern "C" void kernel_launch(void* const* d_in, const int* in_sizes, int n_in,
                              void* d_out, int out_size, void* d_ws, size_t ws_size,
                              hipStream_t stream) {
    const float* b1   = (const float*)d_in[0];  // [B, NV]
    const float* wt1  = (const float*)d_in[1];  // [B, NH, NV]
    const float* muh2 = (const float*)d_in[2];  // [B, NH]
    const float* cov  = (const float*)d_in[3];  // [B, NH]

    // d_out = concat(b2 [B*NV], wt2 [B*NH*NV]) in reference return order.
    float* b2  = (float*)d_out;
    float* wt2 = (float*)d_out + (size_t)NB * NV;

    convert_params_kernel<<<NB, 256, 0, stream>>>(b1, wt1, muh2, cov, b2, wt2);
}